// Round 6
// baseline (276.521 us; speedup 1.0000x reference)
//
#include <hip/hip_runtime.h>
#include <hip/hip_bf16.h>

namespace {
constexpr int kHW   = 40;
constexpr int kNPIX = kHW * kHW;        // 1600
constexpr int kDIM  = 256;
constexpr int kPADW = 42;
constexpr int kACOL = 648;              // heads * 9 * 9
constexpr float kSCALE = 0.17677669529663687f;  // 32^-0.5
}

using bf16 = __hip_bfloat16;
typedef __attribute__((ext_vector_type(8))) short sh8;    // 8 bf16 (A/B frag)
typedef __attribute__((ext_vector_type(4))) float f32x4;  // C/D frag

static __device__ __forceinline__ bf16 f2bf(float f)  { return __float2bfloat16(f); }
static __device__ __forceinline__ float bf2f(bf16 b)  { return __bfloat162float(b); }

// ---------------------------------------------------------------------------
// ONE fused prep kernel (segmented grid, block-uniform branches):
//  [0,1024)     : 4 conv weights  W[oc][ic][3][3] f32 -> Wt[tap][oc][ic] bf16
//  [1024,1360)  : Wfg/Wbg [256][648] f32 -> [672][256] bf16 (cols>=648 zeroed)
//  [1360,1488)  : Wv/Wp   [256][256] f32 -> transposed bf16
//  [1488,2288)  : fg/bg CHW f32 -> HWC bf16 [1600][256]
//  [2288,2688)  : x CHW f32 -> padded HWC bf16 interior
//  [2688,2852)  : zero borders of Pb0/Pb1
__global__ __launch_bounds__(256) void prep_all(
    const float* __restrict__ Wc1, const float* __restrict__ Wc2,
    const float* __restrict__ Wc3, const float* __restrict__ Wc4,
    const float* __restrict__ Wfg, const float* __restrict__ Wbg,
    const float* __restrict__ Wv,  const float* __restrict__ Wp,
    const float* __restrict__ x,   const float* __restrict__ fg,
    const float* __restrict__ bg,
    bf16* __restrict__ Wt1, bf16* __restrict__ Wt2,
    bf16* __restrict__ Wt3, bf16* __restrict__ Wt4,
    bf16* __restrict__ WaTf, bf16* __restrict__ WaTb,
    bf16* __restrict__ WvT, bf16* __restrict__ WpT,
    bf16* __restrict__ SHf, bf16* __restrict__ SHb,
    bf16* __restrict__ Pb0, bf16* __restrict__ Pb1) {
  __shared__ float smem[2304];
  int b = blockIdx.x, t = threadIdx.x;

  if (b < 1024) {                       // conv weight transform
    int w = b >> 8, oc = b & 255;
    const float* src = (w == 0) ? Wc1 : (w == 1) ? Wc2 : (w == 2) ? Wc3 : Wc4;
    bf16* dst        = (w == 0) ? Wt1 : (w == 1) ? Wt2 : (w == 2) ? Wt3 : Wt4;
    src += (size_t)oc * 2304;
    for (int i = t; i < 2304; i += 256) smem[i] = src[i];
    __syncthreads();
#pragma unroll
    for (int tap = 0; tap < 9; ++tap)
      dst[(size_t)(tap * 256 + oc) * 256 + t] = f2bf(smem[t * 9 + tap]);
    return;
  }

  float (*tile)[33] = (float(*)[33])smem;
  int tx = t & 31, ty = t >> 5;

  if (b < 1360) {                       // Wa transposes (R=256, C=648 -> 672x256)
    int b2 = b - 1024;
    const float* in = (b2 < 168) ? Wfg : Wbg;
    bf16* outp      = (b2 < 168) ? WaTf : WaTb;
    int rb = b2 % 168;
    int bx = rb % 21, by = rb / 21;
    int c0 = bx * 32, r0 = by * 32;
#pragma unroll
    for (int rr = ty; rr < 32; rr += 8) {
      int c = c0 + tx;
      tile[rr][tx] = (c < kACOL) ? in[(size_t)(r0 + rr) * kACOL + c] : 0.f;
    }
    __syncthreads();
#pragma unroll
    for (int rr = ty; rr < 32; rr += 8)
      outp[(size_t)(c0 + rr) * 256 + r0 + tx] = f2bf(tile[tx][rr]);
    return;
  }

  if (b < 1488) {                       // Wv / Wp transpose (256x256)
    int b3 = b - 1360;
    const float* in = (b3 < 64) ? Wv : Wp;
    bf16* outp      = (b3 < 64) ? WvT : WpT;
    int rb = b3 & 63;
    int bx = rb & 7, by = rb >> 3;
    int c0 = bx * 32, r0 = by * 32;
#pragma unroll
    for (int rr = ty; rr < 32; rr += 8)
      tile[rr][tx] = in[(size_t)(r0 + rr) * 256 + c0 + tx];
    __syncthreads();
#pragma unroll
    for (int rr = ty; rr < 32; rr += 8)
      outp[(size_t)(c0 + rr) * 256 + r0 + tx] = f2bf(tile[tx][rr]);
    return;
  }

  if (b < 2288) {                       // fg/bg CHW -> HWC bf16
    int b4 = b - 1488;
    const float* in = (b4 < 400) ? fg : bg;
    bf16* outp      = (b4 < 400) ? SHf : SHb;
    int rb = b4 % 400;
    int bx = rb % 50, by = rb / 50;
    int c0 = bx * 32, r0 = by * 32;
#pragma unroll
    for (int rr = ty; rr < 32; rr += 8)
      tile[rr][tx] = in[(size_t)(r0 + rr) * kNPIX + c0 + tx];
    __syncthreads();
#pragma unroll
    for (int rr = ty; rr < 32; rr += 8)
      outp[(size_t)(c0 + rr) * 256 + r0 + tx] = f2bf(tile[tx][rr]);
    return;
  }

  if (b < 2688) {                       // x CHW -> padded HWC bf16 interior
    int b5 = b - 2288;
    int bx = b5 % 50, by = b5 / 50;
    int c0 = bx * 32, r0 = by * 32;
#pragma unroll
    for (int rr = ty; rr < 32; rr += 8)
      tile[rr][tx] = x[(size_t)(r0 + rr) * kNPIX + c0 + tx];
    __syncthreads();
#pragma unroll
    for (int rr = ty; rr < 32; rr += 8) {
      int l = c0 + rr;
      int yy = l / kHW, xx = l % kHW;
      Pb0[(size_t)((yy + 1) * kPADW + xx + 1) * kDIM + r0 + tx] = f2bf(tile[tx][rr]);
    }
    return;
  }

  {                                     // zero pad borders of Pb0 & Pb1
    int k = b - 2688;                   // 0..163
    int py, px;
    if (k < 42)      { py = 0;         px = k; }
    else if (k < 84) { py = 41;        px = k - 42; }
    else if (k < 124){ py = k - 84 + 1; px = 0; }
    else             { py = k - 124 + 1; px = 41; }
    size_t off = (size_t)(py * kPADW + px) * kDIM + t;
    Pb0[off] = f2bf(0.f);
    Pb1[off] = f2bf(0.f);
  }
}

// ---------------------------------------------------------------------------
// MFMA implicit-GEMM 3x3 conv + scale/shift + ReLU (verified structure).
__global__ __launch_bounds__(256) void conv_mfma(const bf16* __restrict__ act,
                                                 const bf16* __restrict__ wt,
                                                 const float* __restrict__ sc,
                                                 const float* __restrict__ sh_,
                                                 bf16* __restrict__ outPad,
                                                 float* __restrict__ outF32) {
  int pt  = blockIdx.x;
  int oc0 = blockIdx.y * 32;
  int ty0 = (pt / 5) * 4;
  int tx0 = (pt % 5) * 8;
  int tid = threadIdx.x;
  int w = tid >> 6, lane = tid & 63, g = lane >> 4, r16 = lane & 15;

  int dy0 = r16 >> 3,       dx0 = r16 & 7;
  int dy1 = 2 + (r16 >> 3), dx1 = r16 & 7;

  f32x4 acc[2][2] = {};
  int icq = w * 64;

#pragma unroll
  for (int t = 0; t < 9; ++t) {
    int tyy = t / 3, txx = t % 3;
    const bf16* aBase0 = act + (size_t)((ty0 + dy0 + tyy) * kPADW + tx0 + dx0 + txx) * kDIM;
    const bf16* aBase1 = act + (size_t)((ty0 + dy1 + tyy) * kPADW + tx0 + dx1 + txx) * kDIM;
    const bf16* bBase  = wt + (size_t)(t * 256 + oc0 + r16) * 256;
#pragma unroll
    for (int kk = 0; kk < 2; ++kk) {
      int ic = icq + kk * 32 + g * 8;
      sh8 a0 = *(const sh8*)(aBase0 + ic);
      sh8 a1 = *(const sh8*)(aBase1 + ic);
      sh8 b0 = *(const sh8*)(bBase + ic);
      sh8 b1 = *(const sh8*)(bBase + 16 * 256 + ic);
      acc[0][0] = __builtin_amdgcn_mfma_f32_16x16x32_bf16(a0, b0, acc[0][0], 0, 0, 0);
      acc[0][1] = __builtin_amdgcn_mfma_f32_16x16x32_bf16(a0, b1, acc[0][1], 0, 0, 0);
      acc[1][0] = __builtin_amdgcn_mfma_f32_16x16x32_bf16(a1, b0, acc[1][0], 0, 0, 0);
      acc[1][1] = __builtin_amdgcn_mfma_f32_16x16x32_bf16(a1, b1, acc[1][1], 0, 0, 0);
    }
  }

  __shared__ float red[4][32][33];
#pragma unroll
  for (int mi = 0; mi < 2; ++mi)
#pragma unroll
    for (int ni = 0; ni < 2; ++ni)
#pragma unroll
      for (int q = 0; q < 4; ++q)
        red[w][mi * 16 + g * 4 + q][ni * 16 + r16] = acc[mi][ni][q];
  __syncthreads();

  int pixL = tid >> 3;
  int ocL  = (tid & 7) * 4;
  int dy = pixL >> 3, dx = pixL & 7;
  int oc = oc0 + ocL;
  int y = ty0 + dy, x = tx0 + dx;
  float v[4];
#pragma unroll
  for (int j = 0; j < 4; ++j) {
    float s = red[0][pixL][ocL + j] + red[1][pixL][ocL + j] +
              red[2][pixL][ocL + j] + red[3][pixL][ocL + j];
    v[j] = fmaxf(fmaf(s, sc[oc + j], sh_[oc + j]), 0.f);
  }
  if (outPad) {
    bf16 pk[4];
#pragma unroll
    for (int j = 0; j < 4; ++j) pk[j] = f2bf(v[j]);
    *reinterpret_cast<uint2*>(outPad + (size_t)((y + 1) * kPADW + x + 1) * kDIM + oc) =
        *reinterpret_cast<uint2*>(pk);
  } else {
#pragma unroll
    for (int j = 0; j < 4; ++j)
      outF32[(oc + j) * kNPIX + y * kHW + x] = v[j];
  }
}

// ---------------------------------------------------------------------------
// Generic MFMA GEMM: out[1600 x N] = A[1600 x 256] @ Bt^T (+bias).
// MODE 0: logits, N=648, f32 out (scaled);  MODE 1: bf16 flat HWC.
template <bool PADDED_A, int MODE>
__global__ __launch_bounds__(256) void gemm_mfma(const bf16* __restrict__ A,
                                                 const bf16* __restrict__ Bt,
                                                 const float* __restrict__ bias,
                                                 float* __restrict__ oF32,
                                                 bf16* __restrict__ oBf) {
  int l0   = blockIdx.x * 32;
  int col0 = blockIdx.y * 32;
  int tid = threadIdx.x;
  int w = tid >> 6, lane = tid & 63, g = lane >> 4, r16 = lane & 15;

  const bf16* aBase[2];
#pragma unroll
  for (int mi = 0; mi < 2; ++mi) {
    int l = l0 + mi * 16 + r16;
    if (PADDED_A) {
      int y = l / kHW, x = l % kHW;
      aBase[mi] = A + (size_t)((y + 1) * kPADW + x + 1) * kDIM;
    } else {
      aBase[mi] = A + (size_t)l * kDIM;
    }
  }
  const bf16* bBase0 = Bt + (size_t)(col0 + r16) * kDIM;
  const bf16* bBase1 = bBase0 + 16 * kDIM;

  f32x4 acc[2][2] = {};
  int icq = w * 64 + g * 8;
#pragma unroll
  for (int kk = 0; kk < 2; ++kk) {
    int ic = icq + kk * 32;
    sh8 a0 = *(const sh8*)(aBase[0] + ic);
    sh8 a1 = *(const sh8*)(aBase[1] + ic);
    sh8 b0 = *(const sh8*)(bBase0 + ic);
    sh8 b1 = *(const sh8*)(bBase1 + ic);
    acc[0][0] = __builtin_amdgcn_mfma_f32_16x16x32_bf16(a0, b0, acc[0][0], 0, 0, 0);
    acc[0][1] = __builtin_amdgcn_mfma_f32_16x16x32_bf16(a0, b1, acc[0][1], 0, 0, 0);
    acc[1][0] = __builtin_amdgcn_mfma_f32_16x16x32_bf16(a1, b0, acc[1][0], 0, 0, 0);
    acc[1][1] = __builtin_amdgcn_mfma_f32_16x16x32_bf16(a1, b1, acc[1][1], 0, 0, 0);
  }

  __shared__ float red[4][32][33];
#pragma unroll
  for (int mi = 0; mi < 2; ++mi)
#pragma unroll
    for (int ni = 0; ni < 2; ++ni)
#pragma unroll
      for (int q = 0; q < 4; ++q)
        red[w][mi * 16 + g * 4 + q][ni * 16 + r16] = acc[mi][ni][q];
  __syncthreads();

  int pixL = tid >> 3;
  int ocL  = (tid & 7) * 4;
  int l = l0 + pixL;
  int col = col0 + ocL;

  float s[4];
#pragma unroll
  for (int j = 0; j < 4; ++j)
    s[j] = red[0][pixL][ocL + j] + red[1][pixL][ocL + j] +
           red[2][pixL][ocL + j] + red[3][pixL][ocL + j];

  if (MODE == 0) {
#pragma unroll
    for (int j = 0; j < 4; ++j)
      if (col + j < kACOL)
        oF32[(size_t)l * kACOL + col + j] = (s[j] + bias[col + j]) * kSCALE;
  } else {
    bf16 pk[4];
#pragma unroll
    for (int j = 0; j < 4; ++j) pk[j] = f2bf(s[j] + bias[col + j]);
    *reinterpret_cast<uint2*>(oBf + (size_t)l * kDIM + col) =
        *reinterpret_cast<uint2*>(pk);
  }
}

// ---------------------------------------------------------------------------
// FUSED fold + projection GEMM.
// Phase 1: fold xw (overlap-add, f32 acc) for this block's 32 pixels -> LDS
//          bf16 [32][264] (row pad +8 -> 4-bank shift/row, 2-way max = free).
// Phase 2: MFMA GEMM folded @ WpT + bp.  MODE 1: flat bf16 HWC; MODE 2: padded.
template <int MODE>
__global__ __launch_bounds__(256) void foldproj_mfma(const bf16* __restrict__ xw,
                                                     const bf16* __restrict__ Bt,
                                                     const float* __restrict__ bias,
                                                     bf16* __restrict__ oBf) {
  __shared__ bf16 fold_s[32][264];
  __shared__ float red[4][32][33];

  int l0   = blockIdx.x * 32;
  int col0 = blockIdx.y * 32;
  int tid = threadIdx.x;

  // fold phase: thread = channel c, loop 32 pixels
  {
    int c = tid;
    for (int s = 0; s < 32; ++s) {
      int l = l0 + s;
      int Y = l / kHW, X = l % kHW;
      float acc = 0.f;
#pragma unroll
      for (int i = 0; i < 3; ++i) {
        int ys = Y + 1 - i;
        if (ys < 0 || ys >= kHW) continue;
#pragma unroll
        for (int j = 0; j < 3; ++j) {
          int xs = X + 1 - j;
          if (xs < 0 || xs >= kHW) continue;
          acc += bf2f(xw[(size_t)((ys * kHW + xs) * 9 + i * 3 + j) * kDIM + c]);
        }
      }
      fold_s[s][c] = f2bf(acc);
    }
  }
  __syncthreads();

  int w = tid >> 6, lane = tid & 63, g = lane >> 4, r16 = lane & 15;
  const bf16* bBase0 = Bt + (size_t)(col0 + r16) * kDIM;
  const bf16* bBase1 = bBase0 + 16 * kDIM;

  f32x4 acc[2][2] = {};
  int icq = w * 64 + g * 8;
#pragma unroll
  for (int kk = 0; kk < 2; ++kk) {
    int ic = icq + kk * 32;
    sh8 a0 = *(const sh8*)(&fold_s[r16][ic]);
    sh8 a1 = *(const sh8*)(&fold_s[16 + r16][ic]);
    sh8 b0 = *(const sh8*)(bBase0 + ic);
    sh8 b1 = *(const sh8*)(bBase1 + ic);
    acc[0][0] = __builtin_amdgcn_mfma_f32_16x16x32_bf16(a0, b0, acc[0][0], 0, 0, 0);
    acc[0][1] = __builtin_amdgcn_mfma_f32_16x16x32_bf16(a0, b1, acc[0][1], 0, 0, 0);
    acc[1][0] = __builtin_amdgcn_mfma_f32_16x16x32_bf16(a1, b0, acc[1][0], 0, 0, 0);
    acc[1][1] = __builtin_amdgcn_mfma_f32_16x16x32_bf16(a1, b1, acc[1][1], 0, 0, 0);
  }

#pragma unroll
  for (int mi = 0; mi < 2; ++mi)
#pragma unroll
    for (int ni = 0; ni < 2; ++ni)
#pragma unroll
      for (int q = 0; q < 4; ++q)
        red[w][mi * 16 + g * 4 + q][ni * 16 + r16] = acc[mi][ni][q];
  __syncthreads();

  int pixL = tid >> 3;
  int ocL  = (tid & 7) * 4;
  int l = l0 + pixL;
  int col = col0 + ocL;

  bf16 pk[4];
#pragma unroll
  for (int j = 0; j < 4; ++j) {
    float s = red[0][pixL][ocL + j] + red[1][pixL][ocL + j] +
              red[2][pixL][ocL + j] + red[3][pixL][ocL + j];
    pk[j] = f2bf(s + bias[col + j]);
  }
  if (MODE == 1) {
    *reinterpret_cast<uint2*>(oBf + (size_t)l * kDIM + col) =
        *reinterpret_cast<uint2*>(pk);
  } else {
    int y = l / kHW, x = l % kHW;
    *reinterpret_cast<uint2*>(oBf + (size_t)((y + 1) * kPADW + x + 1) * kDIM + col) =
        *reinterpret_cast<uint2*>(pk);
  }
}

// ---------------------------------------------------------------------------
// softmax over q per (head,p) + PV. Logits f32 [l][648]; v bf16 HWC.
__global__ __launch_bounds__(256) void softmax_pv(const float* __restrict__ Lg,
                                                  const bf16* __restrict__ v_hwc,
                                                  bf16* __restrict__ xw) {
  __shared__ float att[kACOL];
  __shared__ float vu[9][kDIM];

  int l = blockIdx.x;
  int y = l / kHW, x = l % kHW;
  int t = threadIdx.x;

#pragma unroll
  for (int r = 0; r < 3; ++r) {
    int a = t + r * 256;
    if (a < kACOL) att[a] = Lg[(size_t)l * kACOL + a];
  }
#pragma unroll
  for (int q = 0; q < 9; ++q) {
    int qy = y + q / 3 - 1;
    int qx = x + q % 3 - 1;
    bool ok = (qy >= 0 && qy < kHW && qx >= 0 && qx < kHW);
    vu[q][t] = ok ? bf2f(v_hwc[(size_t)(qy * kHW + qx) * kDIM + t]) : 0.f;
  }
  __syncthreads();

  if (t < 72) {
    float* gp = &att[t * 9];
    float m = gp[0];
#pragma unroll
    for (int q = 1; q < 9; ++q) m = fmaxf(m, gp[q]);
    float e[9], sm = 0.f;
#pragma unroll
    for (int q = 0; q < 9; ++q) { e[q] = __expf(gp[q] - m); sm += e[q]; }
    float inv = 1.f / sm;
#pragma unroll
    for (int q = 0; q < 9; ++q) gp[q] = e[q] * inv;
  }
  __syncthreads();

  int n = t >> 5;
  const float* an = &att[n * 81];
#pragma unroll
  for (int p = 0; p < 9; ++p) {
    float acc = 0.f;
#pragma unroll
    for (int q = 0; q < 9; ++q)
      acc = fmaf(an[p * 9 + q], vu[q][t], acc);
    xw[(size_t)(l * 9 + p) * kDIM + t] = f2bf(acc);
  }
}

// ---------------------------------------------------------------------------
extern "C" void kernel_launch(void* const* d_in, const int* in_sizes, int n_in,
                              void* d_out, int out_size, void* d_ws, size_t ws_size,
                              hipStream_t stream) {
  const float* x   = (const float*)d_in[0];
  const float* fg  = (const float*)d_in[1];
  const float* bg  = (const float*)d_in[2];
  const float* Wc1 = (const float*)d_in[3];
  const float* s1  = (const float*)d_in[4];
  const float* b1  = (const float*)d_in[5];
  const float* Wc2 = (const float*)d_in[6];
  const float* s2  = (const float*)d_in[7];
  const float* b2  = (const float*)d_in[8];
  const float* Wv  = (const float*)d_in[9];
  const float* bv  = (const float*)d_in[10];
  const float* Wfg = (const float*)d_in[11];
  const float* bfg = (const float*)d_in[12];
  const float* Wbg = (const float*)d_in[13];
  const float* bbg = (const float*)d_in[14];
  const float* Wp  = (const float*)d_in[15];
  const float* bp  = (const float*)d_in[16];
  const float* Wc3 = (const float*)d_in[17];
  const float* s3  = (const float*)d_in[18];
  const float* b3  = (const float*)d_in[19];
  const float* Wc4 = (const float*)d_in[20];
  const float* s4  = (const float*)d_in[21];
  const float* b4  = (const float*)d_in[22];
  float* out = (float*)d_out;   // f32 NCHW

  float* ws = (float*)d_ws;
  float* Lg   = ws;                         // 1600x648 f32   (1036800 w)
  bf16* XWb   = (bf16*)(ws + 1036800);      // 3686400 bf16   (1843200 w)
  bf16* SHf   = (bf16*)(ws + 2880000);      // 409600 bf16    (204800 w)
  bf16* SHb   = (bf16*)(ws + 3084800);      // 409600 bf16
  bf16* Vb    = (bf16*)(ws + 3289600);      // v bf16 HWC
  bf16* X1b   = (bf16*)(ws + 3494400);      // x1 bf16 HWC
  bf16* Wt1   = (bf16*)(ws + 3699200);      // 4 x 589824 bf16
  bf16* Wt2   = Wt1 + 589824;
  bf16* Wt3   = Wt2 + 589824;
  bf16* Wt4   = Wt3 + 589824;
  bf16* WaTf  = (bf16*)(ws + 4878848);      // 672x256 bf16
  bf16* WaTb  = (bf16*)(ws + 4964864);
  bf16* WvT   = (bf16*)(ws + 5050880);      // 256x256 bf16
  bf16* WpT   = (bf16*)(ws + 5083648);
  bf16* Pb0   = (bf16*)(ws + 5116416);      // padded HWC bf16 (451584)
  bf16* Pb1   = (bf16*)(ws + 5342208);
  // end: 5568000 words = 22.27 MB

  // one fused prep dispatch (weights, transposes, padding, borders)
  prep_all<<<2852, 256, 0, stream>>>(Wc1, Wc2, Wc3, Wc4, Wfg, Wbg, Wv, Wp,
                                     x, fg, bg,
                                     Wt1, Wt2, Wt3, Wt4, WaTf, WaTb, WvT, WpT,
                                     SHf, SHb, Pb0, Pb1);

  const dim3 convGrid(50, 8);
  const dim3 gemmN256(50, 8);
  const dim3 gemmN648(50, 21);

  // input_cbr
  conv_mfma<<<convGrid, 256, 0, stream>>>(Pb0, Wt1, s1, b1, Pb1, nullptr);
  conv_mfma<<<convGrid, 256, 0, stream>>>(Pb1, Wt2, s2, b2, Pb0, nullptr);  // h0

  // v = h0 @ Wv + bv  (bf16 HWC)
  gemm_mfma<true, 1><<<gemmN256, 256, 0, stream>>>(Pb0, WvT, bv, nullptr, Vb);

  // fg attention pass
  gemm_mfma<false, 0><<<gemmN648, 256, 0, stream>>>(SHf, WaTf, bfg, Lg, nullptr);
  softmax_pv<<<kNPIX, 256, 0, stream>>>(Lg, Vb, XWb);
  foldproj_mfma<1><<<gemmN256, 256, 0, stream>>>(XWb, WpT, bp, X1b);        // x1

  // bg attention pass (v = x1)
  gemm_mfma<false, 0><<<gemmN648, 256, 0, stream>>>(SHb, WaTb, bbg, Lg, nullptr);
  softmax_pv<<<kNPIX, 256, 0, stream>>>(Lg, X1b, XWb);
  foldproj_mfma<2><<<gemmN256, 256, 0, stream>>>(XWb, WpT, bp, Pb1);        // x2 padded

  // output_cbr
  conv_mfma<<<convGrid, 256, 0, stream>>>(Pb1, Wt3, s3, b3, Pb0, nullptr);
  conv_mfma<<<convGrid, 256, 0, stream>>>(Pb0, Wt4, s4, b4, nullptr, out);
}

// Round 7
// 131.326 us; speedup vs baseline: 2.1056x; 2.1056x over previous
//
#include <hip/hip_runtime.h>
#include <hip/hip_bf16.h>

namespace {
constexpr int kHW   = 40;
constexpr int kNPIX = kHW * kHW;        // 1600
constexpr int kDIM  = 256;
constexpr int kPADW = 42;
constexpr int kACOL = 648;              // heads * 9 * 9
constexpr float kSCALE = 0.17677669529663687f;  // 32^-0.5
}

using bf16 = __hip_bfloat16;
typedef __attribute__((ext_vector_type(8))) short sh8;    // 8 bf16 (A/B frag)
typedef __attribute__((ext_vector_type(4))) float f32x4;  // C/D frag

static __device__ __forceinline__ bf16 f2bf(float f)  { return __float2bfloat16(f); }
static __device__ __forceinline__ float bf2f(bf16 b)  { return __bfloat162float(b); }

// ---------------------------------------------------------------------------
// ONE fused prep kernel (segmented grid, block-uniform branches).
__global__ __launch_bounds__(256) void prep_all(
    const float* __restrict__ Wc1, const float* __restrict__ Wc2,
    const float* __restrict__ Wc3, const float* __restrict__ Wc4,
    const float* __restrict__ Wfg, const float* __restrict__ Wbg,
    const float* __restrict__ Wv,  const float* __restrict__ Wp,
    const float* __restrict__ x,   const float* __restrict__ fg,
    const float* __restrict__ bg,
    bf16* __restrict__ Wt1, bf16* __restrict__ Wt2,
    bf16* __restrict__ Wt3, bf16* __restrict__ Wt4,
    bf16* __restrict__ WaTf, bf16* __restrict__ WaTb,
    bf16* __restrict__ WvT, bf16* __restrict__ WpT,
    bf16* __restrict__ SHf, bf16* __restrict__ SHb,
    bf16* __restrict__ Pb0, bf16* __restrict__ Pb1) {
  __shared__ float smem[2304];
  int b = blockIdx.x, t = threadIdx.x;

  if (b < 1024) {                       // conv weight transform
    int w = b >> 8, oc = b & 255;
    const float* src = (w == 0) ? Wc1 : (w == 1) ? Wc2 : (w == 2) ? Wc3 : Wc4;
    bf16* dst        = (w == 0) ? Wt1 : (w == 1) ? Wt2 : (w == 2) ? Wt3 : Wt4;
    src += (size_t)oc * 2304;
    for (int i = t; i < 2304; i += 256) smem[i] = src[i];
    __syncthreads();
#pragma unroll
    for (int tap = 0; tap < 9; ++tap)
      dst[(size_t)(tap * 256 + oc) * 256 + t] = f2bf(smem[t * 9 + tap]);
    return;
  }

  float (*tile)[33] = (float(*)[33])smem;
  int tx = t & 31, ty = t >> 5;

  if (b < 1360) {                       // Wa transposes (256x648 -> 672x256)
    int b2 = b - 1024;
    const float* in = (b2 < 168) ? Wfg : Wbg;
    bf16* outp      = (b2 < 168) ? WaTf : WaTb;
    int rb = b2 % 168;
    int bx = rb % 21, by = rb / 21;
    int c0 = bx * 32, r0 = by * 32;
#pragma unroll
    for (int rr = ty; rr < 32; rr += 8) {
      int c = c0 + tx;
      tile[rr][tx] = (c < kACOL) ? in[(size_t)(r0 + rr) * kACOL + c] : 0.f;
    }
    __syncthreads();
#pragma unroll
    for (int rr = ty; rr < 32; rr += 8)
      outp[(size_t)(c0 + rr) * 256 + r0 + tx] = f2bf(tile[tx][rr]);
    return;
  }

  if (b < 1488) {                       // Wv / Wp transpose (256x256)
    int b3 = b - 1360;
    const float* in = (b3 < 64) ? Wv : Wp;
    bf16* outp      = (b3 < 64) ? WvT : WpT;
    int rb = b3 & 63;
    int bx = rb & 7, by = rb >> 3;
    int c0 = bx * 32, r0 = by * 32;
#pragma unroll
    for (int rr = ty; rr < 32; rr += 8)
      tile[rr][tx] = in[(size_t)(r0 + rr) * 256 + c0 + tx];
    __syncthreads();
#pragma unroll
    for (int rr = ty; rr < 32; rr += 8)
      outp[(size_t)(c0 + rr) * 256 + r0 + tx] = f2bf(tile[tx][rr]);
    return;
  }

  if (b < 2288) {                       // fg/bg CHW -> HWC bf16
    int b4 = b - 1488;
    const float* in = (b4 < 400) ? fg : bg;
    bf16* outp      = (b4 < 400) ? SHf : SHb;
    int rb = b4 % 400;
    int bx = rb % 50, by = rb / 50;
    int c0 = bx * 32, r0 = by * 32;
#pragma unroll
    for (int rr = ty; rr < 32; rr += 8)
      tile[rr][tx] = in[(size_t)(r0 + rr) * kNPIX + c0 + tx];
    __syncthreads();
#pragma unroll
    for (int rr = ty; rr < 32; rr += 8)
      outp[(size_t)(c0 + rr) * 256 + r0 + tx] = f2bf(tile[tx][rr]);
    return;
  }

  if (b < 2688) {                       // x CHW -> padded HWC bf16 interior
    int b5 = b - 2288;
    int bx = b5 % 50, by = b5 / 50;
    int c0 = bx * 32, r0 = by * 32;
#pragma unroll
    for (int rr = ty; rr < 32; rr += 8)
      tile[rr][tx] = x[(size_t)(r0 + rr) * kNPIX + c0 + tx];
    __syncthreads();
#pragma unroll
    for (int rr = ty; rr < 32; rr += 8) {
      int l = c0 + rr;
      int yy = l / kHW, xx = l % kHW;
      Pb0[(size_t)((yy + 1) * kPADW + xx + 1) * kDIM + r0 + tx] = f2bf(tile[tx][rr]);
    }
    return;
  }

  {                                     // zero pad borders of Pb0 & Pb1
    int k = b - 2688;                   // 0..163
    int py, px;
    if (k < 42)      { py = 0;         px = k; }
    else if (k < 84) { py = 41;        px = k - 42; }
    else if (k < 124){ py = k - 84 + 1; px = 0; }
    else             { py = k - 124 + 1; px = 41; }
    size_t off = (size_t)(py * kPADW + px) * kDIM + t;
    Pb0[off] = f2bf(0.f);
    Pb1[off] = f2bf(0.f);
  }
}

// ---------------------------------------------------------------------------
// MFMA implicit-GEMM 3x3 conv + scale/shift + ReLU (verified structure).
__global__ __launch_bounds__(256) void conv_mfma(const bf16* __restrict__ act,
                                                 const bf16* __restrict__ wt,
                                                 const float* __restrict__ sc,
                                                 const float* __restrict__ sh_,
                                                 bf16* __restrict__ outPad,
                                                 float* __restrict__ outF32) {
  int pt  = blockIdx.x;
  int oc0 = blockIdx.y * 32;
  int ty0 = (pt / 5) * 4;
  int tx0 = (pt % 5) * 8;
  int tid = threadIdx.x;
  int w = tid >> 6, lane = tid & 63, g = lane >> 4, r16 = lane & 15;

  int dy0 = r16 >> 3,       dx0 = r16 & 7;
  int dy1 = 2 + (r16 >> 3), dx1 = r16 & 7;

  f32x4 acc[2][2] = {};
  int icq = w * 64;

#pragma unroll
  for (int t = 0; t < 9; ++t) {
    int tyy = t / 3, txx = t % 3;
    const bf16* aBase0 = act + (size_t)((ty0 + dy0 + tyy) * kPADW + tx0 + dx0 + txx) * kDIM;
    const bf16* aBase1 = act + (size_t)((ty0 + dy1 + tyy) * kPADW + tx0 + dx1 + txx) * kDIM;
    const bf16* bBase  = wt + (size_t)(t * 256 + oc0 + r16) * 256;
#pragma unroll
    for (int kk = 0; kk < 2; ++kk) {
      int ic = icq + kk * 32 + g * 8;
      sh8 a0 = *(const sh8*)(aBase0 + ic);
      sh8 a1 = *(const sh8*)(aBase1 + ic);
      sh8 b0 = *(const sh8*)(bBase + ic);
      sh8 b1 = *(const sh8*)(bBase + 16 * 256 + ic);
      acc[0][0] = __builtin_amdgcn_mfma_f32_16x16x32_bf16(a0, b0, acc[0][0], 0, 0, 0);
      acc[0][1] = __builtin_amdgcn_mfma_f32_16x16x32_bf16(a0, b1, acc[0][1], 0, 0, 0);
      acc[1][0] = __builtin_amdgcn_mfma_f32_16x16x32_bf16(a1, b0, acc[1][0], 0, 0, 0);
      acc[1][1] = __builtin_amdgcn_mfma_f32_16x16x32_bf16(a1, b1, acc[1][1], 0, 0, 0);
    }
  }

  __shared__ float red[4][32][33];
#pragma unroll
  for (int mi = 0; mi < 2; ++mi)
#pragma unroll
    for (int ni = 0; ni < 2; ++ni)
#pragma unroll
      for (int q = 0; q < 4; ++q)
        red[w][mi * 16 + g * 4 + q][ni * 16 + r16] = acc[mi][ni][q];
  __syncthreads();

  int pixL = tid >> 3;
  int ocL  = (tid & 7) * 4;
  int dy = pixL >> 3, dx = pixL & 7;
  int oc = oc0 + ocL;
  int y = ty0 + dy, x = tx0 + dx;
  float v[4];
#pragma unroll
  for (int j = 0; j < 4; ++j) {
    float s = red[0][pixL][ocL + j] + red[1][pixL][ocL + j] +
              red[2][pixL][ocL + j] + red[3][pixL][ocL + j];
    v[j] = fmaxf(fmaf(s, sc[oc + j], sh_[oc + j]), 0.f);
  }
  if (outPad) {
    bf16 pk[4];
#pragma unroll
    for (int j = 0; j < 4; ++j) pk[j] = f2bf(v[j]);
    *reinterpret_cast<uint2*>(outPad + (size_t)((y + 1) * kPADW + x + 1) * kDIM + oc) =
        *reinterpret_cast<uint2*>(pk);
  } else {
#pragma unroll
    for (int j = 0; j < 4; ++j)
      outF32[(oc + j) * kNPIX + y * kHW + x] = v[j];
  }
}

// ---------------------------------------------------------------------------
// Merged triple GEMM (segmented grid, block-uniform branches):
//  [0,400)      : v = h0(padded) @ WvT + bv      -> Vb bf16 flat HWC
//  [400,1450)   : logitsF = SHf @ WaTf + bfg     -> LgF bf16 (scaled)
//  [1450,2500)  : logitsB = SHb @ WaTb + bbg     -> LgB bf16 (scaled)
__global__ __launch_bounds__(256) void gemm3_mfma(
    const bf16* __restrict__ Pb0, const bf16* __restrict__ WvT,
    const float* __restrict__ bv, bf16* __restrict__ Vb,
    const bf16* __restrict__ SHf, const bf16* __restrict__ WaTf,
    const float* __restrict__ bfg, bf16* __restrict__ LgF,
    const bf16* __restrict__ SHb, const bf16* __restrict__ WaTb,
    const float* __restrict__ bbg, bf16* __restrict__ LgB) {
  int b = blockIdx.x;
  const bf16 *A, *Bt;
  const float* bias;
  bf16 *oV = nullptr, *oLg = nullptr;
  bool padded = false;
  int l0, col0;
  if (b < 400) {
    padded = true; A = Pb0; Bt = WvT; bias = bv; oV = Vb;
    l0 = (b % 50) * 32; col0 = (b / 50) * 32;
  } else if (b < 1450) {
    int b2 = b - 400;
    A = SHf; Bt = WaTf; bias = bfg; oLg = LgF;
    l0 = (b2 % 50) * 32; col0 = (b2 / 50) * 32;
  } else {
    int b2 = b - 1450;
    A = SHb; Bt = WaTb; bias = bbg; oLg = LgB;
    l0 = (b2 % 50) * 32; col0 = (b2 / 50) * 32;
  }

  int tid = threadIdx.x;
  int w = tid >> 6, lane = tid & 63, g = lane >> 4, r16 = lane & 15;

  const bf16* aBase[2];
#pragma unroll
  for (int mi = 0; mi < 2; ++mi) {
    int l = l0 + mi * 16 + r16;
    if (padded) {
      int y = l / kHW, x = l % kHW;
      aBase[mi] = A + (size_t)((y + 1) * kPADW + x + 1) * kDIM;
    } else {
      aBase[mi] = A + (size_t)l * kDIM;
    }
  }
  const bf16* bBase0 = Bt + (size_t)(col0 + r16) * kDIM;
  const bf16* bBase1 = bBase0 + 16 * kDIM;

  f32x4 acc[2][2] = {};
  int icq = w * 64 + g * 8;
#pragma unroll
  for (int kk = 0; kk < 2; ++kk) {
    int ic = icq + kk * 32;
    sh8 a0 = *(const sh8*)(aBase[0] + ic);
    sh8 a1 = *(const sh8*)(aBase[1] + ic);
    sh8 b0 = *(const sh8*)(bBase0 + ic);
    sh8 b1 = *(const sh8*)(bBase1 + ic);
    acc[0][0] = __builtin_amdgcn_mfma_f32_16x16x32_bf16(a0, b0, acc[0][0], 0, 0, 0);
    acc[0][1] = __builtin_amdgcn_mfma_f32_16x16x32_bf16(a0, b1, acc[0][1], 0, 0, 0);
    acc[1][0] = __builtin_amdgcn_mfma_f32_16x16x32_bf16(a1, b0, acc[1][0], 0, 0, 0);
    acc[1][1] = __builtin_amdgcn_mfma_f32_16x16x32_bf16(a1, b1, acc[1][1], 0, 0, 0);
  }

  __shared__ float red[4][32][33];
#pragma unroll
  for (int mi = 0; mi < 2; ++mi)
#pragma unroll
    for (int ni = 0; ni < 2; ++ni)
#pragma unroll
      for (int q = 0; q < 4; ++q)
        red[w][mi * 16 + g * 4 + q][ni * 16 + r16] = acc[mi][ni][q];
  __syncthreads();

  int pixL = tid >> 3;
  int ocL  = (tid & 7) * 4;
  int l = l0 + pixL;
  int col = col0 + ocL;

  float s[4];
#pragma unroll
  for (int j = 0; j < 4; ++j)
    s[j] = red[0][pixL][ocL + j] + red[1][pixL][ocL + j] +
           red[2][pixL][ocL + j] + red[3][pixL][ocL + j];

  if (oLg) {
#pragma unroll
    for (int j = 0; j < 4; ++j)
      if (col + j < kACOL)
        oLg[(size_t)l * kACOL + col + j] = f2bf((s[j] + bias[col + j]) * kSCALE);
  } else {
    bf16 pk[4];
#pragma unroll
    for (int j = 0; j < 4; ++j) pk[j] = f2bf(s[j] + bias[col + j]);
    *reinterpret_cast<uint2*>(oV + (size_t)l * kDIM + col) =
        *reinterpret_cast<uint2*>(pk);
  }
}

// ---------------------------------------------------------------------------
// Projection GEMM: out[1600x256] = FD @ WpT^T + bp.
// MODE 1: bf16 flat HWC; MODE 2: bf16 padded HWC.
template <int MODE>
__global__ __launch_bounds__(256) void gemm_mfma(const bf16* __restrict__ A,
                                                 const bf16* __restrict__ Bt,
                                                 const float* __restrict__ bias,
                                                 bf16* __restrict__ oBf) {
  int l0   = blockIdx.x * 32;
  int col0 = blockIdx.y * 32;
  int tid = threadIdx.x;
  int w = tid >> 6, lane = tid & 63, g = lane >> 4, r16 = lane & 15;

  const bf16* aBase[2];
#pragma unroll
  for (int mi = 0; mi < 2; ++mi)
    aBase[mi] = A + (size_t)(l0 + mi * 16 + r16) * kDIM;
  const bf16* bBase0 = Bt + (size_t)(col0 + r16) * kDIM;
  const bf16* bBase1 = bBase0 + 16 * kDIM;

  f32x4 acc[2][2] = {};
  int icq = w * 64 + g * 8;
#pragma unroll
  for (int kk = 0; kk < 2; ++kk) {
    int ic = icq + kk * 32;
    sh8 a0 = *(const sh8*)(aBase[0] + ic);
    sh8 a1 = *(const sh8*)(aBase[1] + ic);
    sh8 b0 = *(const sh8*)(bBase0 + ic);
    sh8 b1 = *(const sh8*)(bBase1 + ic);
    acc[0][0] = __builtin_amdgcn_mfma_f32_16x16x32_bf16(a0, b0, acc[0][0], 0, 0, 0);
    acc[0][1] = __builtin_amdgcn_mfma_f32_16x16x32_bf16(a0, b1, acc[0][1], 0, 0, 0);
    acc[1][0] = __builtin_amdgcn_mfma_f32_16x16x32_bf16(a1, b0, acc[1][0], 0, 0, 0);
    acc[1][1] = __builtin_amdgcn_mfma_f32_16x16x32_bf16(a1, b1, acc[1][1], 0, 0, 0);
  }

  __shared__ float red[4][32][33];
#pragma unroll
  for (int mi = 0; mi < 2; ++mi)
#pragma unroll
    for (int ni = 0; ni < 2; ++ni)
#pragma unroll
      for (int q = 0; q < 4; ++q)
        red[w][mi * 16 + g * 4 + q][ni * 16 + r16] = acc[mi][ni][q];
  __syncthreads();

  int pixL = tid >> 3;
  int ocL  = (tid & 7) * 4;
  int l = l0 + pixL;
  int col = col0 + ocL;

  bf16 pk[4];
#pragma unroll
  for (int j = 0; j < 4; ++j) {
    float s = red[0][pixL][ocL + j] + red[1][pixL][ocL + j] +
              red[2][pixL][ocL + j] + red[3][pixL][ocL + j];
    pk[j] = f2bf(s + bias[col + j]);
  }
  if (MODE == 1) {
    *reinterpret_cast<uint2*>(oBf + (size_t)l * kDIM + col) =
        *reinterpret_cast<uint2*>(pk);
  } else {
    int y = l / kHW, x = l % kHW;
    *reinterpret_cast<uint2*>(oBf + (size_t)((y + 1) * kPADW + x + 1) * kDIM + col) =
        *reinterpret_cast<uint2*>(pk);
  }
}

// ---------------------------------------------------------------------------
// softmax over q per (head,p) + PV. Logits bf16 [l][648]; v bf16 HWC.
__global__ __launch_bounds__(256) void softmax_pv(const bf16* __restrict__ Lg,
                                                  const bf16* __restrict__ v_hwc,
                                                  bf16* __restrict__ xw) {
  __shared__ float att[kACOL];
  __shared__ float vu[9][kDIM];

  int l = blockIdx.x;
  int y = l / kHW, x = l % kHW;
  int t = threadIdx.x;

#pragma unroll
  for (int r = 0; r < 3; ++r) {
    int a = t + r * 256;
    if (a < kACOL) att[a] = bf2f(Lg[(size_t)l * kACOL + a]);
  }
#pragma unroll
  for (int q = 0; q < 9; ++q) {
    int qy = y + q / 3 - 1;
    int qx = x + q % 3 - 1;
    bool ok = (qy >= 0 && qy < kHW && qx >= 0 && qx < kHW);
    vu[q][t] = ok ? bf2f(v_hwc[(size_t)(qy * kHW + qx) * kDIM + t]) : 0.f;
  }
  __syncthreads();

  if (t < 72) {
    float* gp = &att[t * 9];
    float m = gp[0];
#pragma unroll
    for (int q = 1; q < 9; ++q) m = fmaxf(m, gp[q]);
    float e[9], sm = 0.f;
#pragma unroll
    for (int q = 0; q < 9; ++q) { e[q] = __expf(gp[q] - m); sm += e[q]; }
    float inv = 1.f / sm;
#pragma unroll
    for (int q = 0; q < 9; ++q) gp[q] = e[q] * inv;
  }
  __syncthreads();

  int n = t >> 5;
  const float* an = &att[n * 81];
#pragma unroll
  for (int p = 0; p < 9; ++p) {
    float acc = 0.f;
#pragma unroll
    for (int q = 0; q < 9; ++q)
      acc = fmaf(an[p * 9 + q], vu[q][t], acc);
    xw[(size_t)(l * 9 + p) * kDIM + t] = f2bf(acc);
  }
}

// ---------------------------------------------------------------------------
// fold: overlap-add gather of xw -> F[1600][256] bf16 (f32 accumulate).
__global__ __launch_bounds__(256) void fold_k(const bf16* __restrict__ xw,
                                              bf16* __restrict__ F) {
  int l = blockIdx.x;
  int Y = l / kHW, X = l % kHW;
  int t = threadIdx.x;
  float acc = 0.f;
#pragma unroll
  for (int i = 0; i < 3; ++i) {
    int ys = Y + 1 - i;
    if (ys < 0 || ys >= kHW) continue;
#pragma unroll
    for (int j = 0; j < 3; ++j) {
      int xs = X + 1 - j;
      if (xs < 0 || xs >= kHW) continue;
      acc += bf2f(xw[(size_t)((ys * kHW + xs) * 9 + i * 3 + j) * kDIM + t]);
    }
  }
  F[(size_t)l * kDIM + t] = f2bf(acc);
}

// ---------------------------------------------------------------------------
extern "C" void kernel_launch(void* const* d_in, const int* in_sizes, int n_in,
                              void* d_out, int out_size, void* d_ws, size_t ws_size,
                              hipStream_t stream) {
  const float* x   = (const float*)d_in[0];
  const float* fg  = (const float*)d_in[1];
  const float* bg  = (const float*)d_in[2];
  const float* Wc1 = (const float*)d_in[3];
  const float* s1  = (const float*)d_in[4];
  const float* b1  = (const float*)d_in[5];
  const float* Wc2 = (const float*)d_in[6];
  const float* s2  = (const float*)d_in[7];
  const float* b2  = (const float*)d_in[8];
  const float* Wv  = (const float*)d_in[9];
  const float* bv  = (const float*)d_in[10];
  const float* Wfg = (const float*)d_in[11];
  const float* bfg = (const float*)d_in[12];
  const float* Wbg = (const float*)d_in[13];
  const float* bbg = (const float*)d_in[14];
  const float* Wp  = (const float*)d_in[15];
  const float* bp  = (const float*)d_in[16];
  const float* Wc3 = (const float*)d_in[17];
  const float* s3  = (const float*)d_in[18];
  const float* b3  = (const float*)d_in[19];
  const float* Wc4 = (const float*)d_in[20];
  const float* s4  = (const float*)d_in[21];
  const float* b4  = (const float*)d_in[22];
  float* out = (float*)d_out;   // f32 NCHW

  float* ws = (float*)d_ws;
  bf16* LgF   = (bf16*)ws;                  // 1600x648 bf16  (518400 w)
  bf16* LgB   = (bf16*)(ws + 518400);       // 1600x648 bf16  (518400 w)
  bf16* XWb   = (bf16*)(ws + 1036800);      // 3686400 bf16   (1843200 w)
  bf16* SHf   = (bf16*)(ws + 2880000);      // 409600 bf16    (204800 w)
  bf16* SHb   = (bf16*)(ws + 3084800);
  bf16* FD    = (bf16*)(ws + 3289600);      // folded bf16
  bf16* Vb    = (bf16*)(ws + 3494400);      // v bf16 HWC
  bf16* X1b   = (bf16*)(ws + 3699200);      // x1 bf16 HWC
  bf16* Wt1   = (bf16*)(ws + 3904000);      // 4 x 589824 bf16
  bf16* Wt2   = Wt1 + 589824;
  bf16* Wt3   = Wt2 + 589824;
  bf16* Wt4   = Wt3 + 589824;
  bf16* WaTf  = (bf16*)(ws + 5083648);      // 672x256 bf16
  bf16* WaTb  = (bf16*)(ws + 5169664);
  bf16* WvT   = (bf16*)(ws + 5255680);      // 256x256 bf16
  bf16* WpT   = (bf16*)(ws + 5288448);
  bf16* Pb0   = (bf16*)(ws + 5321216);      // padded HWC bf16 (451584)
  bf16* Pb1   = (bf16*)(ws + 5547008);
  // end: 5772800 words = 23.09 MB (same budget as the proven round-4 layout)

  // 1) fused prep (weights, transposes, padding, borders)
  prep_all<<<2852, 256, 0, stream>>>(Wc1, Wc2, Wc3, Wc4, Wfg, Wbg, Wv, Wp,
                                     x, fg, bg,
                                     Wt1, Wt2, Wt3, Wt4, WaTf, WaTb, WvT, WpT,
                                     SHf, SHb, Pb0, Pb1);

  const dim3 convGrid(50, 8);
  const dim3 gemmN256(50, 8);

  // 2,3) input_cbr
  conv_mfma<<<convGrid, 256, 0, stream>>>(Pb0, Wt1, s1, b1, Pb1, nullptr);
  conv_mfma<<<convGrid, 256, 0, stream>>>(Pb1, Wt2, s2, b2, Pb0, nullptr);  // h0

  // 4) merged: v = h0@Wv ; logitsF = SHf@Wfg ; logitsB = SHb@Wbg
  gemm3_mfma<<<2500, 256, 0, stream>>>(Pb0, WvT, bv, Vb,
                                       SHf, WaTf, bfg, LgF,
                                       SHb, WaTb, bbg, LgB);

  // 5-7) fg attention pass
  softmax_pv<<<kNPIX, 256, 0, stream>>>(LgF, Vb, XWb);
  fold_k<<<kNPIX, 256, 0, stream>>>(XWb, FD);
  gemm_mfma<1><<<gemmN256, 256, 0, stream>>>(FD, WpT, bp, X1b);   // x1

  // 8-10) bg attention pass (v = x1)
  softmax_pv<<<kNPIX, 256, 0, stream>>>(LgB, X1b, XWb);
  fold_k<<<kNPIX, 256, 0, stream>>>(XWb, FD);
  gemm_mfma<2><<<gemmN256, 256, 0, stream>>>(FD, WpT, bp, Pb1);   // x2 padded

  // 11,12) output_cbr
  conv_mfma<<<convGrid, 256, 0, stream>>>(Pb1, Wt3, s3, b3, Pb0, nullptr);
  conv_mfma<<<convGrid, 256, 0, stream>>>(Pb0, Wt4, s4, b4, nullptr, out);
}